// Round 9
// baseline (239.053 us; speedup 1.0000x reference)
//
#include <hip/hip_runtime.h>
#include <hip/hip_bf16.h>

// GAT layer: B=4, N=2048, F=128, U=64, H=4.
//  k0: pack adj (64MB int32) -> bitmask (2MB)
//  k1: proj GEMM (vector fp32) -> pT_hi/pT_lo bf16 [h][b][u][n] (trunc-split
//      fp32), transposed through LDS for coalesced stores; s[h][b][n] f32
//  k2: MFMA attention, BARRIER-FREE main loop: B fragments loaded straight
//      from global into registers, double-buffered across j-steps (named
//      bufA/bufB, static indices). Per-lane loads are line-efficient: lanes
//      (q,li) with same li cover one contiguous 64B line. w=adj?exp(si*sj):0
//      in-register trunc-split; 3-product split-bf16 MFMA (err ~2^-17).
//      D layout per verified m89. LDS only for sj + padded adj bits.
//  k3: combine: out = 0.25 * sum_h (sum_jc P) / (sum_jc Z)
//
// d_ws layout (bytes), total ~27.7 MB:
//   pT_hi    @ 0          : H*B*U*N bf16 = 4,194,304
//   pT_lo    @ 4,194,304  : H*B*U*N bf16 = 4,194,304
//   s        @ 8,388,608  : H*B*N   f32  =   131,072
//   adjbits  @ 8,519,680  : B*N*N/8      = 2,097,152
//   out_part @ 10,616,832 : H*JC*B*N*U f32 = 16,777,216
//   Z_part   @ 27,394,048 : H*JC*B*N f32 = 262,144

#define Bdim 4
#define Ndim 2048
#define Fdim 128
#define Udim 64
#define Hdim 4
#define JC 2
#define JCHUNK (Ndim / JC)  // 1024

typedef __attribute__((ext_vector_type(8))) short short8;
typedef __attribute__((ext_vector_type(4))) float f32x4;

__device__ __forceinline__ short bf16_rne(float f) {
  union { __hip_bfloat16 b; unsigned short u; } c;
  c.b = __float2bfloat16(f);
  return (short)c.u;
}

// trunc split: hi = f's high 16 bits (exact by truncation),
// lo = bf16_rne(f - float(hi)). hi+lo represents f to ~2^-17 rel.
__device__ __forceinline__ void splitbf(float f, short& hi, short& lo) {
  unsigned u = __float_as_uint(f);
  hi = (short)(u >> 16);
  float lof = f - __uint_as_float(u & 0xffff0000u);
  lo = bf16_rne(lof);
}

// ---------------- k0: pack adjacency to bitmask ----------------
__global__ __launch_bounds__(256) void pack_adj_kernel(
    const int* __restrict__ adj, unsigned long long* __restrict__ bits,
    int nchunks) {
  const int lane = threadIdx.x & 63;
  const int wid = (blockIdx.x * 256 + threadIdx.x) >> 6;
  const int nw = (gridDim.x * 256) >> 6;
  for (int c = wid * 4; c + 3 < nchunks; c += nw * 4) {
    int v0 = adj[(size_t)(c + 0) * 64 + lane];
    int v1 = adj[(size_t)(c + 1) * 64 + lane];
    int v2 = adj[(size_t)(c + 2) * 64 + lane];
    int v3 = adj[(size_t)(c + 3) * 64 + lane];
    unsigned long long m0 = __ballot(v0 != 0);
    unsigned long long m1 = __ballot(v1 != 0);
    unsigned long long m2 = __ballot(v2 != 0);
    unsigned long long m3 = __ballot(v3 != 0);
    if (lane == 0) {
      bits[c + 0] = m0;
      bits[c + 1] = m1;
      bits[c + 2] = m2;
      bits[c + 3] = m3;
    }
  }
}

// ---------------- k1: projection -> split-bf16 transposed + s ----------------
__global__ __launch_bounds__(256) void proj_kernel(
    const float* __restrict__ x, const float* __restrict__ W,
    const float* __restrict__ bias, const float* __restrict__ a_w,
    const float* __restrict__ a_b, unsigned short* __restrict__ pTh,
    unsigned short* __restrict__ pTl, float* __restrict__ s) {
  const int bid = blockIdx.x;
  const int nt = bid & 31;
  const int b = (bid >> 5) & 3;
  const int h = bid >> 7;
  const int n0 = nt * 64;

  __shared__ __align__(16) char smem[71168];
  float (*Wl)[Udim] = (float(*)[Udim])(smem);                  // 32768 B
  float (*xl)[Fdim + 4] = (float(*)[Fdim + 4])(smem + 32768);  // 33792 B
  float (*pt)[68] = (float(*)[68])(smem + 32768);              // alias xl
  float* bl = (float*)(smem + 66560);
  float* awl = (float*)(smem + 66816);
  float (*sred)[16] = (float(*)[16])(smem + 67072);            // 4096 B

  const int t = threadIdx.x;

  const float* Wg = W + (size_t)h * Fdim * Udim;
  for (int k = t; k < Fdim * Udim / 4; k += 256) {
    ((float4*)&Wl[0][0])[k] = ((const float4*)Wg)[k];
  }
  if (t < Udim) {
    bl[t] = bias[h * Udim + t];
    awl[t] = a_w[h * Udim + t];
  }
  const float* xg = x + ((size_t)b * Ndim + n0) * Fdim;
  for (int k = t; k < 64 * Fdim / 4; k += 256) {
    int row = k >> 5;
    int c4 = k & 31;
    float4 v = ((const float4*)xg)[(size_t)row * (Fdim / 4) + c4];
    *(float4*)&xl[row][c4 * 4] = v;
  }
  __syncthreads();

  const int ug = t & 15, rg = t >> 4;
  const int u0 = ug * 4, r0 = rg * 4;
  float acc[4][4] = {};

#pragma unroll 4
  for (int f = 0; f < Fdim; ++f) {
    const float4 wv = *(const float4*)&Wl[f][u0];
    const float xv[4] = {xl[r0][f], xl[r0 + 1][f], xl[r0 + 2][f], xl[r0 + 3][f]};
#pragma unroll
    for (int c = 0; c < 4; ++c) {
      acc[c][0] = fmaf(xv[c], wv.x, acc[c][0]);
      acc[c][1] = fmaf(xv[c], wv.y, acc[c][1]);
      acc[c][2] = fmaf(xv[c], wv.z, acc[c][2]);
      acc[c][3] = fmaf(xv[c], wv.w, acc[c][3]);
    }
  }

  float po[4][4];  // [c = n-offset][k = u-offset]
#pragma unroll
  for (int c = 0; c < 4; ++c)
#pragma unroll
    for (int k = 0; k < 4; ++k)
      po[c][k] = fmaxf(acc[c][k] + bl[u0 + k], 0.f);

#pragma unroll
  for (int c = 0; c < 4; ++c) {
    float sp = po[c][0] * awl[u0 + 0] + po[c][1] * awl[u0 + 1] +
               po[c][2] * awl[u0 + 2] + po[c][3] * awl[u0 + 3];
    sred[r0 + c][ug] = sp;
  }
  __syncthreads();  // all xl reads done; safe to overwrite via pt alias

#pragma unroll
  for (int k = 0; k < 4; ++k) {
    float4 v = {po[0][k], po[1][k], po[2][k], po[3][k]};
    *(float4*)&pt[u0 + k][r0] = v;
  }
  __syncthreads();

  const size_t hb = (size_t)h * Bdim + b;
  const int su = t >> 2;
  const int snl = (t & 3) * 16;
  float v[16];
#pragma unroll
  for (int j = 0; j < 4; ++j)
    *(float4*)&v[4 * j] = *(const float4*)&pt[su][snl + 4 * j];
  short hi[16], lo[16];
#pragma unroll
  for (int k = 0; k < 16; ++k) splitbf(v[k], hi[k], lo[k]);
  unsigned short* ph =
      pTh + hb * (size_t)(Udim * Ndim) + (size_t)su * Ndim + n0 + snl;
  unsigned short* pl =
      pTl + hb * (size_t)(Udim * Ndim) + (size_t)su * Ndim + n0 + snl;
  *(short8*)(ph + 0) = *(short8*)&hi[0];
  *(short8*)(ph + 8) = *(short8*)&hi[8];
  *(short8*)(pl + 0) = *(short8*)&lo[0];
  *(short8*)(pl + 8) = *(short8*)&lo[8];

  if (t < 64) {
    float sum = a_b[h];
#pragma unroll
    for (int k = 0; k < 16; ++k) sum += sred[t][k];
    s[hb * Ndim + n0 + t] = sum;
  }
}

// ---------------- k2: MFMA masked-softmax aggregation, barrier-free --------
// grid: 1024 blocks = (h:4, b:4, itile:32, jc:2), 256 threads (4 waves).
// Each wave independent: owns i-rows [i0g+wv*16,+16), loads its own B
// fragments from global (L2-resident) into double-buffered registers.
// No __syncthreads in the main loop.
#define LOADB(dst, JS)                                       \
  do {                                                       \
    dst[0] = *(const short8*)(bhp + 0 * 16 * Ndim + (JS));   \
    dst[1] = *(const short8*)(blp + 0 * 16 * Ndim + (JS));   \
    dst[2] = *(const short8*)(bhp + 1 * 16 * Ndim + (JS));   \
    dst[3] = *(const short8*)(blp + 1 * 16 * Ndim + (JS));   \
    dst[4] = *(const short8*)(bhp + 2 * 16 * Ndim + (JS));   \
    dst[5] = *(const short8*)(blp + 2 * 16 * Ndim + (JS));   \
    dst[6] = *(const short8*)(bhp + 3 * 16 * Ndim + (JS));   \
    dst[7] = *(const short8*)(blp + 3 * 16 * Ndim + (JS));   \
  } while (0)

#define STEP(buf, JS)                                                          \
  do {                                                                         \
    const unsigned int mb = (ab[irow][(JS) >> 5] >> (q * 8)) & 0xffu;          \
    const f32x4 s0 = *(const f32x4*)&sj[(JS) + q * 8];                         \
    const f32x4 s1 = *(const f32x4*)&sj[(JS) + q * 8 + 4];                     \
    const float sv[8] = {s0.x, s0.y, s0.z, s0.w, s1.x, s1.y, s1.z, s1.w};      \
    short8 ahi, alo;                                                           \
    _Pragma("unroll") for (int e = 0; e < 8; ++e) {                            \
      float we = __expf(si * sv[e]);                                           \
      we = ((mb >> e) & 1u) ? we : 0.f;                                        \
      zacc += we;                                                              \
      short hh, ll;                                                            \
      splitbf(we, hh, ll);                                                     \
      ahi[e] = hh;                                                             \
      alo[e] = ll;                                                             \
    }                                                                          \
    __builtin_amdgcn_s_setprio(1);                                             \
    acc[0] = __builtin_amdgcn_mfma_f32_16x16x32_bf16(ahi, buf[0], acc[0],0,0,0);\
    acc[1] = __builtin_amdgcn_mfma_f32_16x16x32_bf16(ahi, buf[2], acc[1],0,0,0);\
    acc[2] = __builtin_amdgcn_mfma_f32_16x16x32_bf16(ahi, buf[4], acc[2],0,0,0);\
    acc[3] = __builtin_amdgcn_mfma_f32_16x16x32_bf16(ahi, buf[6], acc[3],0,0,0);\
    acc[0] = __builtin_amdgcn_mfma_f32_16x16x32_bf16(alo, buf[0], acc[0],0,0,0);\
    acc[1] = __builtin_amdgcn_mfma_f32_16x16x32_bf16(alo, buf[2], acc[1],0,0,0);\
    acc[2] = __builtin_amdgcn_mfma_f32_16x16x32_bf16(alo, buf[4], acc[2],0,0,0);\
    acc[3] = __builtin_amdgcn_mfma_f32_16x16x32_bf16(alo, buf[6], acc[3],0,0,0);\
    acc[0] = __builtin_amdgcn_mfma_f32_16x16x32_bf16(ahi, buf[1], acc[0],0,0,0);\
    acc[1] = __builtin_amdgcn_mfma_f32_16x16x32_bf16(ahi, buf[3], acc[1],0,0,0);\
    acc[2] = __builtin_amdgcn_mfma_f32_16x16x32_bf16(ahi, buf[5], acc[2],0,0,0);\
    acc[3] = __builtin_amdgcn_mfma_f32_16x16x32_bf16(ahi, buf[7], acc[3],0,0,0);\
    __builtin_amdgcn_s_setprio(0);                                             \
  } while (0)

__global__ __launch_bounds__(256, 3) void attn_mfma_kernel(
    const unsigned short* __restrict__ pTh,
    const unsigned short* __restrict__ pTl, const float* __restrict__ s,
    const unsigned int* __restrict__ abits, float* __restrict__ out_part,
    float* __restrict__ Z_part) {
  const int bid = blockIdx.x;
  const int jc = bid & 1;
  const int it = (bid >> 1) & 31;
  const int b = (bid >> 6) & 3;
  const int h = bid >> 8;
  const int i0g = it * 64;
  const int j0g = jc * JCHUNK;

  __shared__ float sj[JCHUNK];         // 4 KB
  __shared__ unsigned int ab[64][33];  // 8.45 KB padded (conflict-free)

  const int t = threadIdx.x;
  const int wv = t >> 6;
  const int lane = t & 63;
  const int q = lane >> 4;
  const int li = lane & 15;
  const size_t hb = (size_t)h * Bdim + b;
  const float* sg = s + hb * Ndim;

  ((float4*)sj)[t] = ((const float4*)(sg + j0g))[t];  // 1024 floats
  for (int k = t; k < 64 * 32; k += 256) {
    int row = k >> 5, w = k & 31;
    ab[row][w] =
        abits[((size_t)b * Ndim + i0g + row) * (Ndim / 32) + (j0g >> 5) + w];
  }
  const int irow = wv * 16 + li;

  // per-lane B base: u-row = wv-independent! B frag lane (q,li): u=li (+m*16)
  const unsigned short* bhp =
      pTh + hb * (size_t)(Udim * Ndim) + (size_t)li * Ndim + j0g + q * 8;
  const unsigned short* blp =
      pTl + hb * (size_t)(Udim * Ndim) + (size_t)li * Ndim + j0g + q * 8;

  f32x4 acc[4] = {};
  float zacc = 0.f;
  short8 bufA[8], bufB[8];
  LOADB(bufA, 0);
  __syncthreads();  // sj/ab staged (single barrier in the whole kernel)

  const float si = sg[i0g + irow];

  for (int js = 0; js < JCHUNK; js += 64) {
    LOADB(bufB, js + 32);
    STEP(bufA, js);
    if (js + 64 < JCHUNK) LOADB(bufA, js + 64);
    STEP(bufB, js + 32);
  }

  // Z: reduce across q (lanes li, li+16, li+32, li+48)
  zacc += __shfl_xor(zacc, 16, 64);
  zacc += __shfl_xor(zacc, 32, 64);
  const size_t pslab = ((size_t)h * JC + jc) * Bdim + b;
  if (q == 0) Z_part[pslab * Ndim + i0g + wv * 16 + li] = zacc;

  // direct C-stores (D layout m89: col=li, row=q*4+r)
  float* op = out_part + (pslab * Ndim + i0g + wv * 16) * Udim;
#pragma unroll
  for (int r = 0; r < 4; ++r) {
    const int ir = q * 4 + r;
#pragma unroll
    for (int m = 0; m < 4; ++m) {
      op[(size_t)ir * Udim + m * 16 + li] = acc[m][r];
    }
  }
}

// ---------------- k3: combine partials, normalize, head-mean ----------------
__global__ __launch_bounds__(256) void combine_kernel(
    const float* __restrict__ out_part, const float* __restrict__ Z_part,
    float* __restrict__ out) {
  const int idx = blockIdx.x * 256 + threadIdx.x;
  const int u4 = idx & 15;
  const size_t bn = (size_t)(idx >> 4);
  float4 r = {0.f, 0.f, 0.f, 0.f};
#pragma unroll
  for (int h = 0; h < Hdim; ++h) {
    float4 p = {0.f, 0.f, 0.f, 0.f};
    float z = 0.f;
#pragma unroll
    for (int j = 0; j < JC; ++j) {
      const size_t sl = ((size_t)h * JC + j) * (Bdim * Ndim) + bn;
      float4 pj = ((const float4*)out_part)[sl * (Udim / 4) + u4];
      p.x += pj.x; p.y += pj.y; p.z += pj.z; p.w += pj.w;
      z += Z_part[sl];
    }
    z = (z != 0.f) ? z : 1.f;
    const float inv = 1.f / z;
    r.x += p.x * inv;
    r.y += p.y * inv;
    r.z += p.z * inv;
    r.w += p.w * inv;
  }
  r.x *= 0.25f; r.y *= 0.25f; r.z *= 0.25f; r.w *= 0.25f;
  ((float4*)out)[idx] = r;
}

extern "C" void kernel_launch(void* const* d_in, const int* in_sizes, int n_in,
                              void* d_out, int out_size, void* d_ws,
                              size_t ws_size, hipStream_t stream) {
  const float* x = (const float*)d_in[0];
  const int* adj = (const int*)d_in[1];
  const float* W = (const float*)d_in[2];
  const float* bias = (const float*)d_in[3];
  const float* a_w = (const float*)d_in[4];
  const float* a_b = (const float*)d_in[5];
  float* out = (float*)d_out;

  char* ws = (char*)d_ws;
  unsigned short* pTh = (unsigned short*)(ws + 0);
  unsigned short* pTl = (unsigned short*)(ws + 4194304);
  float* s = (float*)(ws + 8388608);
  unsigned int* adjbits = (unsigned int*)(ws + 8519680);
  float* out_part = (float*)(ws + 10616832);
  float* Z_part = (float*)(ws + 27394048);

  const int nchunks = Bdim * Ndim * Ndim / 64;  // 262144
  pack_adj_kernel<<<2048, 256, 0, stream>>>(adj, (unsigned long long*)adjbits,
                                            nchunks);
  proj_kernel<<<Hdim * Bdim * 32, 256, 0, stream>>>(x, W, bias, a_w, a_b, pTh,
                                                    pTl, s);
  attn_mfma_kernel<<<Hdim * Bdim * 32 * JC, 256, 0, stream>>>(
      pTh, pTl, s, adjbits, out_part, Z_part);
  combine_kernel<<<(Bdim * Ndim * Udim / 4) / 256, 256, 0, stream>>>(
      out_part, Z_part, out);
}

// Round 10
// 178.798 us; speedup vs baseline: 1.3370x; 1.3370x over previous
//
#include <hip/hip_runtime.h>
#include <hip/hip_bf16.h>

// GAT layer: B=4, N=2048, F=128, U=64, H=4.
//  k0: pack adj (64MB int32) -> bitmask (2MB)
//  k1: proj GEMM (vector fp32) -> pT_hi/pT_lo bf16 [h][b][u][n] (trunc-split
//      fp32), transposed through LDS for coalesced stores; s[h][b][n] f32
//  k2: MFMA attention, JC=4 (grid 2048, occupancy), LDS-staged B via
//      global_load_lds (proven R5 pattern, static dual buffers), padded
//      ab[64][17] (conflict-free), 3-product split-bf16 MFMA, LDS-bounced
//      vectorized C-stores (kills write-allocate refetch, R6-proven).
//  k3: combine: out = 0.25 * sum_h (sum_jc P) / (sum_jc Z)
//
// d_ws layout (bytes), total 44,695,552:
//   pT_hi    @ 0          : H*B*U*N bf16 = 4,194,304
//   pT_lo    @ 4,194,304  : H*B*U*N bf16 = 4,194,304
//   s        @ 8,388,608  : H*B*N   f32  =   131,072
//   adjbits  @ 8,519,680  : B*N*N/8      = 2,097,152
//   out_part @ 10,616,832 : H*JC*B*N*U f32 = 33,554,432
//   Z_part   @ 44,171,264 : H*JC*B*N f32 = 524,288

#define Bdim 4
#define Ndim 2048
#define Fdim 128
#define Udim 64
#define Hdim 4
#define JC 4
#define JCHUNK (Ndim / JC)  // 512

typedef __attribute__((ext_vector_type(8))) short short8;
typedef __attribute__((ext_vector_type(4))) float f32x4;

__device__ __forceinline__ short bf16_rne(float f) {
  union { __hip_bfloat16 b; unsigned short u; } c;
  c.b = __float2bfloat16(f);
  return (short)c.u;
}

// trunc split: hi = f's high 16 bits (exact by truncation),
// lo = bf16_rne(f - float(hi)). hi+lo represents f to ~2^-17 rel.
__device__ __forceinline__ void splitbf(float f, short& hi, short& lo) {
  unsigned u = __float_as_uint(f);
  hi = (short)(u >> 16);
  float lof = f - __uint_as_float(u & 0xffff0000u);
  lo = bf16_rne(lof);
}

// async global->LDS, 16B per lane; dest = wave-uniform base + lane*16
__device__ __forceinline__ void stage16(const void* g, void* l) {
  __builtin_amdgcn_global_load_lds(
      (const __attribute__((address_space(1))) unsigned int*)g,
      (__attribute__((address_space(3))) unsigned int*)l, 16, 0, 0);
}

// ---------------- k0: pack adjacency to bitmask ----------------
__global__ __launch_bounds__(256) void pack_adj_kernel(
    const int* __restrict__ adj, unsigned long long* __restrict__ bits,
    int nchunks) {
  const int lane = threadIdx.x & 63;
  const int wid = (blockIdx.x * 256 + threadIdx.x) >> 6;
  const int nw = (gridDim.x * 256) >> 6;
  for (int c = wid * 4; c + 3 < nchunks; c += nw * 4) {
    int v0 = adj[(size_t)(c + 0) * 64 + lane];
    int v1 = adj[(size_t)(c + 1) * 64 + lane];
    int v2 = adj[(size_t)(c + 2) * 64 + lane];
    int v3 = adj[(size_t)(c + 3) * 64 + lane];
    unsigned long long m0 = __ballot(v0 != 0);
    unsigned long long m1 = __ballot(v1 != 0);
    unsigned long long m2 = __ballot(v2 != 0);
    unsigned long long m3 = __ballot(v3 != 0);
    if (lane == 0) {
      bits[c + 0] = m0;
      bits[c + 1] = m1;
      bits[c + 2] = m2;
      bits[c + 3] = m3;
    }
  }
}

// ---------------- k1: projection -> split-bf16 transposed + s ----------------
__global__ __launch_bounds__(256) void proj_kernel(
    const float* __restrict__ x, const float* __restrict__ W,
    const float* __restrict__ bias, const float* __restrict__ a_w,
    const float* __restrict__ a_b, unsigned short* __restrict__ pTh,
    unsigned short* __restrict__ pTl, float* __restrict__ s) {
  const int bid = blockIdx.x;
  const int nt = bid & 31;
  const int b = (bid >> 5) & 3;
  const int h = bid >> 7;
  const int n0 = nt * 64;

  __shared__ __align__(16) char smem[71168];
  float (*Wl)[Udim] = (float(*)[Udim])(smem);                  // 32768 B
  float (*xl)[Fdim + 4] = (float(*)[Fdim + 4])(smem + 32768);  // 33792 B
  float (*pt)[68] = (float(*)[68])(smem + 32768);              // alias xl
  float* bl = (float*)(smem + 66560);
  float* awl = (float*)(smem + 66816);
  float (*sred)[16] = (float(*)[16])(smem + 67072);            // 4096 B

  const int t = threadIdx.x;

  const float* Wg = W + (size_t)h * Fdim * Udim;
  for (int k = t; k < Fdim * Udim / 4; k += 256) {
    ((float4*)&Wl[0][0])[k] = ((const float4*)Wg)[k];
  }
  if (t < Udim) {
    bl[t] = bias[h * Udim + t];
    awl[t] = a_w[h * Udim + t];
  }
  const float* xg = x + ((size_t)b * Ndim + n0) * Fdim;
  for (int k = t; k < 64 * Fdim / 4; k += 256) {
    int row = k >> 5;
    int c4 = k & 31;
    float4 v = ((const float4*)xg)[(size_t)row * (Fdim / 4) + c4];
    *(float4*)&xl[row][c4 * 4] = v;
  }
  __syncthreads();

  const int ug = t & 15, rg = t >> 4;
  const int u0 = ug * 4, r0 = rg * 4;
  float acc[4][4] = {};

#pragma unroll 4
  for (int f = 0; f < Fdim; ++f) {
    const float4 wv = *(const float4*)&Wl[f][u0];
    const float xv[4] = {xl[r0][f], xl[r0 + 1][f], xl[r0 + 2][f], xl[r0 + 3][f]};
#pragma unroll
    for (int c = 0; c < 4; ++c) {
      acc[c][0] = fmaf(xv[c], wv.x, acc[c][0]);
      acc[c][1] = fmaf(xv[c], wv.y, acc[c][1]);
      acc[c][2] = fmaf(xv[c], wv.z, acc[c][2]);
      acc[c][3] = fmaf(xv[c], wv.w, acc[c][3]);
    }
  }

  float po[4][4];  // [c = n-offset][k = u-offset]
#pragma unroll
  for (int c = 0; c < 4; ++c)
#pragma unroll
    for (int k = 0; k < 4; ++k)
      po[c][k] = fmaxf(acc[c][k] + bl[u0 + k], 0.f);

#pragma unroll
  for (int c = 0; c < 4; ++c) {
    float sp = po[c][0] * awl[u0 + 0] + po[c][1] * awl[u0 + 1] +
               po[c][2] * awl[u0 + 2] + po[c][3] * awl[u0 + 3];
    sred[r0 + c][ug] = sp;
  }
  __syncthreads();  // all xl reads done; safe to overwrite via pt alias

#pragma unroll
  for (int k = 0; k < 4; ++k) {
    float4 v = {po[0][k], po[1][k], po[2][k], po[3][k]};
    *(float4*)&pt[u0 + k][r0] = v;
  }
  __syncthreads();

  const size_t hb = (size_t)h * Bdim + b;
  const int su = t >> 2;
  const int snl = (t & 3) * 16;
  float v[16];
#pragma unroll
  for (int j = 0; j < 4; ++j)
    *(float4*)&v[4 * j] = *(const float4*)&pt[su][snl + 4 * j];
  short hi[16], lo[16];
#pragma unroll
  for (int k = 0; k < 16; ++k) splitbf(v[k], hi[k], lo[k]);
  unsigned short* ph =
      pTh + hb * (size_t)(Udim * Ndim) + (size_t)su * Ndim + n0 + snl;
  unsigned short* pl =
      pTl + hb * (size_t)(Udim * Ndim) + (size_t)su * Ndim + n0 + snl;
  *(short8*)(ph + 0) = *(short8*)&hi[0];
  *(short8*)(ph + 8) = *(short8*)&hi[8];
  *(short8*)(pl + 0) = *(short8*)&lo[0];
  *(short8*)(pl + 8) = *(short8*)&lo[8];

  if (t < 64) {
    float sum = a_b[h];
#pragma unroll
    for (int k = 0; k < 16; ++k) sum += sred[t][k];
    s[hb * Ndim + n0 + t] = sum;
  }
}

// ---------------- k2: MFMA masked-softmax aggregation ----------------
// grid: 2048 blocks = (h:4, b:4, itile:32, jc:4), 256 threads (4 waves).
// LDS 22.3 KB; launch_bounds(256,6) -> up to 6 blocks/CU resident.
// Per 32-j step: wave wv stages u-tile wv (hi+lo) for next step via
// global_load_lds into the other static buffer; exp/split in regs; 12 MFMA.
#define ASTEP(BBASE, JS)                                                       \
  do {                                                                         \
    const unsigned int mb = (ab[irow][(JS) >> 5] >> (q * 8)) & 0xffu;          \
    const f32x4 s0 = *(const f32x4*)&sj[(JS) + q * 8];                         \
    const f32x4 s1 = *(const f32x4*)&sj[(JS) + q * 8 + 4];                     \
    const float sv[8] = {s0.x, s0.y, s0.z, s0.w, s1.x, s1.y, s1.z, s1.w};      \
    short8 ahi, alo;                                                           \
    _Pragma("unroll") for (int e = 0; e < 8; ++e) {                            \
      float we = __expf(si * sv[e]);                                           \
      we = ((mb >> e) & 1u) ? we : 0.f;                                        \
      zacc += we;                                                              \
      short hh, ll;                                                            \
      splitbf(we, hh, ll);                                                     \
      ahi[e] = hh;                                                             \
      alo[e] = ll;                                                             \
    }                                                                          \
    const short8 b0h = *(const short8*)((BBASE) + 0 * 512 + lane * 8);         \
    const short8 b0l = *(const short8*)((BBASE) + 1 * 512 + lane * 8);         \
    const short8 b1h = *(const short8*)((BBASE) + 2 * 512 + lane * 8);         \
    const short8 b1l = *(const short8*)((BBASE) + 3 * 512 + lane * 8);         \
    const short8 b2h = *(const short8*)((BBASE) + 4 * 512 + lane * 8);         \
    const short8 b2l = *(const short8*)((BBASE) + 5 * 512 + lane * 8);         \
    const short8 b3h = *(const short8*)((BBASE) + 6 * 512 + lane * 8);         \
    const short8 b3l = *(const short8*)((BBASE) + 7 * 512 + lane * 8);         \
    __builtin_amdgcn_s_setprio(1);                                             \
    acc[0] = __builtin_amdgcn_mfma_f32_16x16x32_bf16(ahi, b0h, acc[0],0,0,0);  \
    acc[1] = __builtin_amdgcn_mfma_f32_16x16x32_bf16(ahi, b1h, acc[1],0,0,0);  \
    acc[2] = __builtin_amdgcn_mfma_f32_16x16x32_bf16(ahi, b2h, acc[2],0,0,0);  \
    acc[3] = __builtin_amdgcn_mfma_f32_16x16x32_bf16(ahi, b3h, acc[3],0,0,0);  \
    acc[0] = __builtin_amdgcn_mfma_f32_16x16x32_bf16(alo, b0h, acc[0],0,0,0);  \
    acc[1] = __builtin_amdgcn_mfma_f32_16x16x32_bf16(alo, b1h, acc[1],0,0,0);  \
    acc[2] = __builtin_amdgcn_mfma_f32_16x16x32_bf16(alo, b2h, acc[2],0,0,0);  \
    acc[3] = __builtin_amdgcn_mfma_f32_16x16x32_bf16(alo, b3h, acc[3],0,0,0);  \
    acc[0] = __builtin_amdgcn_mfma_f32_16x16x32_bf16(ahi, b0l, acc[0],0,0,0);  \
    acc[1] = __builtin_amdgcn_mfma_f32_16x16x32_bf16(ahi, b1l, acc[1],0,0,0);  \
    acc[2] = __builtin_amdgcn_mfma_f32_16x16x32_bf16(ahi, b2l, acc[2],0,0,0);  \
    acc[3] = __builtin_amdgcn_mfma_f32_16x16x32_bf16(ahi, b3l, acc[3],0,0,0);  \
    __builtin_amdgcn_s_setprio(0);                                             \
  } while (0)

__global__ __launch_bounds__(256, 6) void attn_mfma_kernel(
    const unsigned short* __restrict__ pTh,
    const unsigned short* __restrict__ pTl, const float* __restrict__ s,
    const unsigned int* __restrict__ abits, float* __restrict__ out_part,
    float* __restrict__ Z_part) {
  const int bid = blockIdx.x;
  const int jc = bid & 3;
  const int it = (bid >> 2) & 31;
  const int b = (bid >> 7) & 3;
  const int h = bid >> 9;
  const int i0g = it * 64;
  const int j0g = jc * JCHUNK;

  // LDS: sj @0 (2048B) | ab[64][17] @2048 (4352B) | Bst0 @6400 (8192B)
  //      | Bst1 @14592 (8192B)  -> 22784B. cbuf aliases @0 (17408B).
  __shared__ __align__(16) char smem[22784];
  float* sj = (float*)smem;
  unsigned int (*ab)[17] = (unsigned int(*)[17])(smem + 2048);
  short* Bst0 = (short*)(smem + 6400);
  short* Bst1 = (short*)(smem + 14592);
  float* cbuf = (float*)smem;  // [4 waves][16 rows][68]

  const int t = threadIdx.x;
  const int wv = t >> 6;
  const int lane = t & 63;
  const int q = lane >> 4;
  const int li = lane & 15;
  const size_t hb = (size_t)h * Bdim + b;
  const float* sg = s + hb * Ndim;

  ((float2*)sj)[t] = ((const float2*)(sg + j0g))[t];  // 512 floats
  {
    const int row = t >> 2, w0 = (t & 3) * 4;
    uint4 v = *(const uint4*)&abits[((size_t)b * Ndim + i0g + row) *
                                        (Ndim / 32) +
                                    jc * 16 + w0];
    ab[row][w0 + 0] = v.x;
    ab[row][w0 + 1] = v.y;
    ab[row][w0 + 2] = v.z;
    ab[row][w0 + 3] = v.w;
  }
  const int irow = wv * 16 + li;

  const unsigned short* bsrc_h =
      pTh + hb * (size_t)(Udim * Ndim) + (size_t)(wv * 16 + li) * Ndim + j0g +
      q * 8;
  const unsigned short* bsrc_l =
      pTl + hb * (size_t)(Udim * Ndim) + (size_t)(wv * 16 + li) * Ndim + j0g +
      q * 8;

  // stage step 0 into Bst0
  stage16(bsrc_h, Bst0 + (wv * 2 + 0) * 512);
  stage16(bsrc_l, Bst0 + (wv * 2 + 1) * 512);

  f32x4 acc[4] = {};
  float zacc = 0.f;
  __syncthreads();  // drains vmcnt: sj, ab, staged B all visible

  const float si = sg[i0g + irow];

  for (int js = 0; js < JCHUNK; js += 64) {
    // stage js+32 into Bst1, compute js from Bst0
    stage16(bsrc_h + js + 32, Bst1 + (wv * 2 + 0) * 512);
    stage16(bsrc_l + js + 32, Bst1 + (wv * 2 + 1) * 512);
    ASTEP(Bst0, js);
    __syncthreads();
    // stage js+64 into Bst0, compute js+32 from Bst1
    if (js + 64 < JCHUNK) {
      stage16(bsrc_h + js + 64, Bst0 + (wv * 2 + 0) * 512);
      stage16(bsrc_l + js + 64, Bst0 + (wv * 2 + 1) * 512);
    }
    ASTEP(Bst1, js + 32);
    __syncthreads();
  }

  // Z: reduce across q (lanes li, li+16, li+32, li+48)
  zacc += __shfl_xor(zacc, 16, 64);
  zacc += __shfl_xor(zacc, 32, 64);
  const size_t pslab = ((size_t)h * JC + jc) * Bdim + b;
  if (q == 0) Z_part[pslab * Ndim + i0g + wv * 16 + li] = zacc;

  // C-write: bounce through LDS (wave-private region, no barrier needed),
  // padded stride 68 (~2-way max), then 16B coalesced stores.
  float* cb = cbuf + wv * 16 * 68;
#pragma unroll
  for (int r = 0; r < 4; ++r)
#pragma unroll
    for (int m = 0; m < 4; ++m)
      cb[(q * 4 + r) * 68 + m * 16 + li] = acc[m][r];
  {
    const int row = lane >> 2, c0 = (lane & 3) * 16;
    const float* src = cb + row * 68 + c0;
    float* op = out_part + (pslab * Ndim + i0g + wv * 16 + row) * Udim + c0;
#pragma unroll
    for (int k = 0; k < 4; ++k)
      *(float4*)(op + k * 4) = *(const float4*)(src + k * 4);
  }
}

// ---------------- k3: combine partials, normalize, head-mean ----------------
__global__ __launch_bounds__(256) void combine_kernel(
    const float* __restrict__ out_part, const float* __restrict__ Z_part,
    float* __restrict__ out) {
  const int idx = blockIdx.x * 256 + threadIdx.x;
  const int u4 = idx & 15;
  const size_t bn = (size_t)(idx >> 4);
  float4 r = {0.f, 0.f, 0.f, 0.f};
#pragma unroll
  for (int h = 0; h < Hdim; ++h) {
    float4 p = {0.f, 0.f, 0.f, 0.f};
    float z = 0.f;
#pragma unroll
    for (int j = 0; j < JC; ++j) {
      const size_t sl = ((size_t)h * JC + j) * (Bdim * Ndim) + bn;
      float4 pj = ((const float4*)out_part)[sl * (Udim / 4) + u4];
      p.x += pj.x; p.y += pj.y; p.z += pj.z; p.w += pj.w;
      z += Z_part[sl];
    }
    z = (z != 0.f) ? z : 1.f;
    const float inv = 1.f / z;
    r.x += p.x * inv;
    r.y += p.y * inv;
    r.z += p.z * inv;
    r.w += p.w * inv;
  }
  r.x *= 0.25f; r.y *= 0.25f; r.z *= 0.25f; r.w *= 0.25f;
  ((float4*)out)[idx] = r;
}

extern "C" void kernel_launch(void* const* d_in, const int* in_sizes, int n_in,
                              void* d_out, int out_size, void* d_ws,
                              size_t ws_size, hipStream_t stream) {
  const float* x = (const float*)d_in[0];
  const int* adj = (const int*)d_in[1];
  const float* W = (const float*)d_in[2];
  const float* bias = (const float*)d_in[3];
  const float* a_w = (const float*)d_in[4];
  const float* a_b = (const float*)d_in[5];
  float* out = (float*)d_out;

  char* ws = (char*)d_ws;
  unsigned short* pTh = (unsigned short*)(ws + 0);
  unsigned short* pTl = (unsigned short*)(ws + 4194304);
  float* s = (float*)(ws + 8388608);
  unsigned int* adjbits = (unsigned int*)(ws + 8519680);
  float* out_part = (float*)(ws + 10616832);
  float* Z_part = (float*)(ws + 44171264);

  const int nchunks = Bdim * Ndim * Ndim / 64;  // 262144
  pack_adj_kernel<<<2048, 256, 0, stream>>>(adj, (unsigned long long*)adjbits,
                                            nchunks);
  proj_kernel<<<Hdim * Bdim * 32, 256, 0, stream>>>(x, W, bias, a_w, a_b, pTh,
                                                    pTl, s);
  attn_mfma_kernel<<<Hdim * Bdim * 32 * JC, 256, 0, stream>>>(
      pTh, pTl, s, adjbits, out_part, Z_part);
  combine_kernel<<<(Bdim * Ndim * Udim / 4) / 256, 256, 0, stream>>>(
      out_part, Z_part, out);
}

// Round 11
// 162.884 us; speedup vs baseline: 1.4676x; 1.0977x over previous
//
#include <hip/hip_runtime.h>
#include <hip/hip_bf16.h>

// GAT layer: B=4, N=2048, F=128, U=64, H=4.
//  k0: pack adj (64MB int32) -> bitmask (2MB)
//  k1: proj GEMM (vector fp32) -> pT_hi/pT_lo bf16 [h][b][u][n] (split fp32),
//      transposed through LDS for coalesced stores; s[h][b][n] f32
//  k2: MFMA attention (R5 structure + T4 counted-vmcnt): triple-buffered
//      global_load_lds staging 2 steps ahead, per-step s_waitcnt vmcnt(2) +
//      raw s_barrier (stage k+1 stays in flight across the barrier).
//      w = adj ? exp2(si2*sj) : 0 in-register, RNE pair-split via
//      __float22bfloat162_rn (pre-packed); 3-product split-bf16 MFMA;
//      Z computed on the MFMA pipe via ones-vector (2 extra MFMA/step).
//      D layout per verified m89.
//  k3: combine: out = 0.25 * sum_h (sum_jc P) / (sum_jc Z)
//
// d_ws layout (bytes), total ~27.7 MB (R5 footprint):
//   pT_hi    @ 0          : H*B*U*N bf16 = 4,194,304
//   pT_lo    @ 4,194,304  : H*B*U*N bf16 = 4,194,304
//   s        @ 8,388,608  : H*B*N   f32  =   131,072
//   adjbits  @ 8,519,680  : B*N*N/8      = 2,097,152
//   out_part @ 10,616,832 : H*JC*B*N*U f32 = 16,777,216
//   Z_part   @ 27,394,048 : H*JC*B*N f32 = 262,144

#define Bdim 4
#define Ndim 2048
#define Fdim 128
#define Udim 64
#define Hdim 4
#define JC 2
#define JCHUNK (Ndim / JC)  // 1024

typedef __attribute__((ext_vector_type(8))) short short8;
typedef __attribute__((ext_vector_type(4))) float f32x4;

__device__ __forceinline__ short bf16_rne(float f) {
  union { __hip_bfloat16 b; unsigned short u; } c;
  c.b = __float2bfloat16(f);
  return (short)c.u;
}

// trunc split (proj only): hi = high 16 bits, lo = bf16_rne(residual)
__device__ __forceinline__ void splitbf(float f, short& hi, short& lo) {
  unsigned u = __float_as_uint(f);
  hi = (short)(u >> 16);
  float lof = f - __uint_as_float(u & 0xffff0000u);
  lo = bf16_rne(lof);
}

// RNE pair split via packed cvt: hi = rne(w), lo = rne(w - float(hi)),
// both pairs land pre-packed in one 32-bit word each.
__device__ __forceinline__ void splitpk(float w0, float w1, unsigned& hiw,
                                        unsigned& low) {
  union { __hip_bfloat162 b; unsigned u; } h, l;
  float2 wp; wp.x = w0; wp.y = w1;
  h.b = __float22bfloat162_rn(wp);
  float2 lp;
  lp.x = w0 - __bfloat162float(h.b.x);
  lp.y = w1 - __bfloat162float(h.b.y);
  l.b = __float22bfloat162_rn(lp);
  hiw = h.u;
  low = l.u;
}

// async global->LDS, 16B per lane; dest = wave-uniform base + lane*16
__device__ __forceinline__ void stage16(const void* g, void* l) {
  __builtin_amdgcn_global_load_lds(
      (const __attribute__((address_space(1))) unsigned int*)g,
      (__attribute__((address_space(3))) unsigned int*)l, 16, 0, 0);
}

// ---------------- k0: pack adjacency to bitmask ----------------
__global__ __launch_bounds__(256) void pack_adj_kernel(
    const int* __restrict__ adj, unsigned long long* __restrict__ bits,
    int nchunks) {
  const int lane = threadIdx.x & 63;
  const int wid = (blockIdx.x * 256 + threadIdx.x) >> 6;
  const int nw = (gridDim.x * 256) >> 6;
  for (int c = wid * 4; c + 3 < nchunks; c += nw * 4) {
    int v0 = adj[(size_t)(c + 0) * 64 + lane];
    int v1 = adj[(size_t)(c + 1) * 64 + lane];
    int v2 = adj[(size_t)(c + 2) * 64 + lane];
    int v3 = adj[(size_t)(c + 3) * 64 + lane];
    unsigned long long m0 = __ballot(v0 != 0);
    unsigned long long m1 = __ballot(v1 != 0);
    unsigned long long m2 = __ballot(v2 != 0);
    unsigned long long m3 = __ballot(v3 != 0);
    if (lane == 0) {
      bits[c + 0] = m0;
      bits[c + 1] = m1;
      bits[c + 2] = m2;
      bits[c + 3] = m3;
    }
  }
}

// ---------------- k1: projection -> split-bf16 transposed + s ----------------
__global__ __launch_bounds__(256) void proj_kernel(
    const float* __restrict__ x, const float* __restrict__ W,
    const float* __restrict__ bias, const float* __restrict__ a_w,
    const float* __restrict__ a_b, unsigned short* __restrict__ pTh,
    unsigned short* __restrict__ pTl, float* __restrict__ s) {
  const int bid = blockIdx.x;
  const int nt = bid & 31;
  const int b = (bid >> 5) & 3;
  const int h = bid >> 7;
  const int n0 = nt * 64;

  __shared__ __align__(16) char smem[71168];
  float (*Wl)[Udim] = (float(*)[Udim])(smem);                  // 32768 B
  float (*xl)[Fdim + 4] = (float(*)[Fdim + 4])(smem + 32768);  // 33792 B
  float (*pt)[68] = (float(*)[68])(smem + 32768);              // alias xl
  float* bl = (float*)(smem + 66560);
  float* awl = (float*)(smem + 66816);
  float (*sred)[16] = (float(*)[16])(smem + 67072);            // 4096 B

  const int t = threadIdx.x;

  const float* Wg = W + (size_t)h * Fdim * Udim;
  for (int k = t; k < Fdim * Udim / 4; k += 256) {
    ((float4*)&Wl[0][0])[k] = ((const float4*)Wg)[k];
  }
  if (t < Udim) {
    bl[t] = bias[h * Udim + t];
    awl[t] = a_w[h * Udim + t];
  }
  const float* xg = x + ((size_t)b * Ndim + n0) * Fdim;
  for (int k = t; k < 64 * Fdim / 4; k += 256) {
    int row = k >> 5;
    int c4 = k & 31;
    float4 v = ((const float4*)xg)[(size_t)row * (Fdim / 4) + c4];
    *(float4*)&xl[row][c4 * 4] = v;
  }
  __syncthreads();

  const int ug = t & 15, rg = t >> 4;
  const int u0 = ug * 4, r0 = rg * 4;
  float acc[4][4] = {};

#pragma unroll 4
  for (int f = 0; f < Fdim; ++f) {
    const float4 wv = *(const float4*)&Wl[f][u0];
    const float xv[4] = {xl[r0][f], xl[r0 + 1][f], xl[r0 + 2][f], xl[r0 + 3][f]};
#pragma unroll
    for (int c = 0; c < 4; ++c) {
      acc[c][0] = fmaf(xv[c], wv.x, acc[c][0]);
      acc[c][1] = fmaf(xv[c], wv.y, acc[c][1]);
      acc[c][2] = fmaf(xv[c], wv.z, acc[c][2]);
      acc[c][3] = fmaf(xv[c], wv.w, acc[c][3]);
    }
  }

  float po[4][4];  // [c = n-offset][k = u-offset]
#pragma unroll
  for (int c = 0; c < 4; ++c)
#pragma unroll
    for (int k = 0; k < 4; ++k)
      po[c][k] = fmaxf(acc[c][k] + bl[u0 + k], 0.f);

#pragma unroll
  for (int c = 0; c < 4; ++c) {
    float sp = po[c][0] * awl[u0 + 0] + po[c][1] * awl[u0 + 1] +
               po[c][2] * awl[u0 + 2] + po[c][3] * awl[u0 + 3];
    sred[r0 + c][ug] = sp;
  }
  __syncthreads();  // all xl reads done; safe to overwrite via pt alias

#pragma unroll
  for (int k = 0; k < 4; ++k) {
    float4 v = {po[0][k], po[1][k], po[2][k], po[3][k]};
    *(float4*)&pt[u0 + k][r0] = v;
  }
  __syncthreads();

  const size_t hb = (size_t)h * Bdim + b;
  const int su = t >> 2;
  const int snl = (t & 3) * 16;
  float v[16];
#pragma unroll
  for (int j = 0; j < 4; ++j)
    *(float4*)&v[4 * j] = *(const float4*)&pt[su][snl + 4 * j];
  short hi[16], lo[16];
#pragma unroll
  for (int k = 0; k < 16; ++k) splitbf(v[k], hi[k], lo[k]);
  unsigned short* ph =
      pTh + hb * (size_t)(Udim * Ndim) + (size_t)su * Ndim + n0 + snl;
  unsigned short* pl =
      pTl + hb * (size_t)(Udim * Ndim) + (size_t)su * Ndim + n0 + snl;
  *(short8*)(ph + 0) = *(short8*)&hi[0];
  *(short8*)(ph + 8) = *(short8*)&hi[8];
  *(short8*)(pl + 0) = *(short8*)&lo[0];
  *(short8*)(pl + 8) = *(short8*)&lo[8];

  if (t < 64) {
    float sum = a_b[h];
#pragma unroll
    for (int k = 0; k < 16; ++k) sum += sred[t][k];
    s[hb * Ndim + n0 + t] = sum;
  }
}

// ---------------- k2: MFMA masked-softmax aggregation ----------------
// grid: 1024 blocks = (h:4, b:4, itile:32, jc:2), 256 threads (4 waves).
// LDS 36.25 KB -> 4 blocks/CU. Triple-buffered staging 2 steps ahead;
// per-step: vmcnt(2) + s_barrier (counted — stage k+1 stays in flight),
// then stage(k+2), exp2/pair-split (registers), 8 ds_read_b128, 14 MFMA
// (12 product + 2 Z-via-ones).
#define ASTEP(BPTR, JS)                                                        \
  do {                                                                         \
    const unsigned int mb = (ab[irow][(JS) >> 5] >> (q * 8)) & 0xffu;          \
    const f32x4 s0 = *(const f32x4*)&sj[(JS) + q * 8];                         \
    const f32x4 s1 = *(const f32x4*)&sj[(JS) + q * 8 + 4];                     \
    const float sv[8] = {s0.x, s0.y, s0.z, s0.w, s1.x, s1.y, s1.z, s1.w};      \
    float w[8];                                                                \
    _Pragma("unroll") for (int e = 0; e < 8; ++e) {                            \
      float we = __builtin_amdgcn_exp2f(si2 * sv[e]);                          \
      w[e] = ((mb >> e) & 1u) ? we : 0.f;                                      \
    }                                                                          \
    union { short8 s8; unsigned u[4]; } ahi, alo;                              \
    _Pragma("unroll") for (int p = 0; p < 4; ++p)                              \
      splitpk(w[2 * p], w[2 * p + 1], ahi.u[p], alo.u[p]);                     \
    const short* bp = (const short*)(BPTR);                                    \
    const short8 b0h = *(const short8*)(bp + 0 * 512 + lane * 8);              \
    const short8 b0l = *(const short8*)(bp + 1 * 512 + lane * 8);              \
    const short8 b1h = *(const short8*)(bp + 2 * 512 + lane * 8);              \
    const short8 b1l = *(const short8*)(bp + 3 * 512 + lane * 8);              \
    const short8 b2h = *(const short8*)(bp + 4 * 512 + lane * 8);              \
    const short8 b2l = *(const short8*)(bp + 5 * 512 + lane * 8);              \
    const short8 b3h = *(const short8*)(bp + 6 * 512 + lane * 8);              \
    const short8 b3l = *(const short8*)(bp + 7 * 512 + lane * 8);              \
    __builtin_amdgcn_s_setprio(1);                                             \
    acc[0] = __builtin_amdgcn_mfma_f32_16x16x32_bf16(ahi.s8, b0h, acc[0],0,0,0);\
    acc[1] = __builtin_amdgcn_mfma_f32_16x16x32_bf16(ahi.s8, b1h, acc[1],0,0,0);\
    acc[2] = __builtin_amdgcn_mfma_f32_16x16x32_bf16(ahi.s8, b2h, acc[2],0,0,0);\
    acc[3] = __builtin_amdgcn_mfma_f32_16x16x32_bf16(ahi.s8, b3h, acc[3],0,0,0);\
    accZ   = __builtin_amdgcn_mfma_f32_16x16x32_bf16(ahi.s8, bones, accZ,0,0,0);\
    acc[0] = __builtin_amdgcn_mfma_f32_16x16x32_bf16(alo.s8, b0h, acc[0],0,0,0);\
    acc[1] = __builtin_amdgcn_mfma_f32_16x16x32_bf16(alo.s8, b1h, acc[1],0,0,0);\
    acc[2] = __builtin_amdgcn_mfma_f32_16x16x32_bf16(alo.s8, b2h, acc[2],0,0,0);\
    acc[3] = __builtin_amdgcn_mfma_f32_16x16x32_bf16(alo.s8, b3h, acc[3],0,0,0);\
    accZ   = __builtin_amdgcn_mfma_f32_16x16x32_bf16(alo.s8, bones, accZ,0,0,0);\
    acc[0] = __builtin_amdgcn_mfma_f32_16x16x32_bf16(ahi.s8, b0l, acc[0],0,0,0);\
    acc[1] = __builtin_amdgcn_mfma_f32_16x16x32_bf16(ahi.s8, b1l, acc[1],0,0,0);\
    acc[2] = __builtin_amdgcn_mfma_f32_16x16x32_bf16(ahi.s8, b2l, acc[2],0,0,0);\
    acc[3] = __builtin_amdgcn_mfma_f32_16x16x32_bf16(ahi.s8, b3l, acc[3],0,0,0);\
    __builtin_amdgcn_s_setprio(0);                                             \
  } while (0)

__global__ __launch_bounds__(256, 4) void attn_mfma_kernel(
    const unsigned short* __restrict__ pTh,
    const unsigned short* __restrict__ pTl, const float* __restrict__ s,
    const unsigned int* __restrict__ abits, float* __restrict__ out_part,
    float* __restrict__ Z_part) {
  const int bid = blockIdx.x;
  const int jc = bid & 1;
  const int it = (bid >> 1) & 31;
  const int b = (bid >> 6) & 3;
  const int h = bid >> 8;
  const int i0g = it * 64;
  const int j0g = jc * JCHUNK;

  __shared__ float sj[JCHUNK];                    // 4 KB
  __shared__ unsigned int ab[64][33];             // 8.45 KB padded
  __shared__ __align__(16) short Bst[3][8][512];  // 24 KB triple buffer

  const int t = threadIdx.x;
  const int wv = t >> 6;
  const int lane = t & 63;
  const int q = lane >> 4;
  const int li = lane & 15;
  const size_t hb = (size_t)h * Bdim + b;
  const float* sg = s + hb * Ndim;

  ((float4*)sj)[t] = ((const float4*)(sg + j0g))[t];  // 1024 floats
  for (int k = t; k < 64 * 32; k += 256) {
    int row = k >> 5, w = k & 31;
    ab[row][w] =
        abits[((size_t)b * Ndim + i0g + row) * (Ndim / 32) + (j0g >> 5) + w];
  }
  const int irow = wv * 16 + li;
  const float si2 = sg[i0g + irow] * 1.4426950408889634f;  // fold log2(e)

  const unsigned short* bsrc_h =
      pTh + hb * (size_t)(Udim * Ndim) + (size_t)(wv * 16 + li) * Ndim + j0g +
      q * 8;
  const unsigned short* bsrc_l =
      pTl + hb * (size_t)(Udim * Ndim) + (size_t)(wv * 16 + li) * Ndim + j0g +
      q * 8;

  __syncthreads();  // sj/ab visible before any wave reads them

  // stage steps 0 and 1 (each wave: u-tile wv, hi+lo)
  stage16(bsrc_h + 0, &Bst[0][wv * 2 + 0][0]);
  stage16(bsrc_l + 0, &Bst[0][wv * 2 + 1][0]);
  stage16(bsrc_h + 32, &Bst[1][wv * 2 + 0][0]);
  stage16(bsrc_l + 32, &Bst[1][wv * 2 + 1][0]);

  f32x4 acc[4] = {};
  f32x4 accZ = {};
  const short8 bones = {16256, 16256, 16256, 16256,
                        16256, 16256, 16256, 16256};  // bf16(1.0) x8

  short* bS0 = &Bst[0][0][0];
  short* bS1 = &Bst[1][0][0];
  short* bS2 = &Bst[2][0][0];

  for (int js = 0; js < JCHUNK; js += 32) {
    // my stage(k) landed (outstanding <= 4: stage k, k+1); stage(k+1) stays
    // in flight across the barrier (T4 counted-vmcnt).
    asm volatile("s_waitcnt vmcnt(2)" ::: "memory");
    __builtin_amdgcn_s_barrier();
    __builtin_amdgcn_sched_barrier(0);
    // stage step k+2 into the buffer freed by step k-1 (wrap keeps the
    // outstanding count uniform in the tail; dummy restage is never read)
    const int jsn = (js + 64) & (JCHUNK - 1);
    stage16(bsrc_h + jsn, bS2 + (wv * 2 + 0) * 512);
    stage16(bsrc_l + jsn, bS2 + (wv * 2 + 1) * 512);
    ASTEP(bS0, js);
    short* tmp = bS0; bS0 = bS1; bS1 = bS2; bS2 = tmp;
  }

  const size_t pslab = ((size_t)h * JC + jc) * Bdim + b;
  // Z from ones-MFMA: all 16 cols of accZ identical; lane li==0 of each q
  // holds rows q*4+r.
  if (li == 0) {
#pragma unroll
    for (int r = 0; r < 4; ++r)
      Z_part[pslab * Ndim + i0g + wv * 16 + q * 4 + r] = accZ[r];
  }

  // direct C-stores (D layout m89: col=li, row=q*4+r)
  float* op = out_part + (pslab * Ndim + i0g + wv * 16) * Udim;
#pragma unroll
  for (int r = 0; r < 4; ++r) {
    const int ir = q * 4 + r;
#pragma unroll
    for (int m = 0; m < 4; ++m) {
      op[(size_t)ir * Udim + m * 16 + li] = acc[m][r];
    }
  }
}

// ---------------- k3: combine partials, normalize, head-mean ----------------
__global__ __launch_bounds__(256) void combine_kernel(
    const float* __restrict__ out_part, const float* __restrict__ Z_part,
    float* __restrict__ out) {
  const int idx = blockIdx.x * 256 + threadIdx.x;
  const int u4 = idx & 15;
  const size_t bn = (size_t)(idx >> 4);
  float4 r = {0.f, 0.f, 0.f, 0.f};
#pragma unroll
  for (int h = 0; h < Hdim; ++h) {
    float4 p = {0.f, 0.f, 0.f, 0.f};
    float z = 0.f;
#pragma unroll
    for (int j = 0; j < JC; ++j) {
      const size_t sl = ((size_t)h * JC + j) * (Bdim * Ndim) + bn;
      float4 pj = ((const float4*)out_part)[sl * (Udim / 4) + u4];
      p.x += pj.x; p.y += pj.y; p.z += pj.z; p.w += pj.w;
      z += Z_part[sl];
    }
    z = (z != 0.f) ? z : 1.f;
    const float inv = 1.f / z;
    r.x += p.x * inv;
    r.y += p.y * inv;
    r.z += p.z * inv;
    r.w += p.w * inv;
  }
  r.x *= 0.25f; r.y *= 0.25f; r.z *= 0.25f; r.w *= 0.25f;
  ((float4*)out)[idx] = r;
}

extern "C" void kernel_launch(void* const* d_in, const int* in_sizes, int n_in,
                              void* d_out, int out_size, void* d_ws,
                              size_t ws_size, hipStream_t stream) {
  const float* x = (const float*)d_in[0];
  const int* adj = (const int*)d_in[1];
  const float* W = (const float*)d_in[2];
  const float* bias = (const float*)d_in[3];
  const float* a_w = (const float*)d_in[4];
  const float* a_b = (const float*)d_in[5];
  float* out = (float*)d_out;

  char* ws = (char*)d_ws;
  unsigned short* pTh = (unsigned short*)(ws + 0);
  unsigned short* pTl = (unsigned short*)(ws + 4194304);
  float* s = (float*)(ws + 8388608);
  unsigned int* adjbits = (unsigned int*)(ws + 8519680);
  float* out_part = (float*)(ws + 10616832);
  float* Z_part = (float*)(ws + 27394048);

  const int nchunks = Bdim * Ndim * Ndim / 64;  // 262144
  pack_adj_kernel<<<2048, 256, 0, stream>>>(adj, (unsigned long long*)adjbits,
                                            nchunks);
  proj_kernel<<<Hdim * Bdim * 32, 256, 0, stream>>>(x, W, bias, a_w, a_b, pTh,
                                                    pTl, s);
  attn_mfma_kernel<<<Hdim * Bdim * 32 * JC, 256, 0, stream>>>(
      pTh, pTl, s, adjbits, out_part, Z_part);
  combine_kernel<<<(Bdim * Ndim * Udim / 4) / 256, 256, 0, stream>>>(
      out_part, Z_part, out);
}

// Round 12
// 148.108 us; speedup vs baseline: 1.6140x; 1.0998x over previous
//
#include <hip/hip_runtime.h>
#include <hip/hip_bf16.h>
#include <hip/hip_fp16.h>

// GAT layer: B=4, N=2048, F=128, U=64, H=4.
//  k0: pack adj (64MB int32) -> bitmask (2MB)
//  k1: proj GEMM (vector fp32) -> pT fp16 [h][b][u][n], s[h][b][n] f32
//  k2: MFMA attention, SINGLE-product fp16 (softmax shift-invariance:
//      w' = exp2(si2*sj - c_i), c_i = |si2|*max_j|s_j| over the FULL row,
//      computed bit-identically by both jc blocks -> partials combine).
//      Triple-buffered global_load_lds (1 KB/wave/step), counted vmcnt(1),
//      5 MFMA/step (4 product + 1 Z-via-ones). XCD swizzle: same-(h,b,jc)
//      blocks -> same XCD (B-slab L2-resident). D layout per verified m89.
//  k3: combine: out = 0.25 * sum_h (sum_jc P) / (sum_jc Z)
//
// d_ws layout (bytes):
//   pT       @ 0          : H*B*U*N f16 = 4,194,304
//   s        @ 4,194,304  : H*B*N   f32 =   131,072
//   adjbits  @ 4,325,376  : B*N*N/8     = 2,097,152
//   out_part @ 6,422,528  : H*JC*B*N*U f32 = 16,777,216
//   Z_part   @ 23,199,744 : H*JC*B*N f32 = 262,144

#define Bdim 4
#define Ndim 2048
#define Fdim 128
#define Udim 64
#define Hdim 4
#define JC 2
#define JCHUNK (Ndim / JC)  // 1024

typedef __attribute__((ext_vector_type(8))) short short8;
typedef __attribute__((ext_vector_type(8))) _Float16 half8;
typedef __attribute__((ext_vector_type(4))) float f32x4;

// async global->LDS, 16B per lane; dest = wave-uniform base + lane*16
__device__ __forceinline__ void stage16(const void* g, void* l) {
  __builtin_amdgcn_global_load_lds(
      (const __attribute__((address_space(1))) unsigned int*)g,
      (__attribute__((address_space(3))) unsigned int*)l, 16, 0, 0);
}

// ---------------- k0: pack adjacency to bitmask ----------------
__global__ __launch_bounds__(256) void pack_adj_kernel(
    const int* __restrict__ adj, unsigned long long* __restrict__ bits,
    int nchunks) {
  const int lane = threadIdx.x & 63;
  const int wid = (blockIdx.x * 256 + threadIdx.x) >> 6;
  const int nw = (gridDim.x * 256) >> 6;
  for (int c = wid * 4; c + 3 < nchunks; c += nw * 4) {
    int v0 = adj[(size_t)(c + 0) * 64 + lane];
    int v1 = adj[(size_t)(c + 1) * 64 + lane];
    int v2 = adj[(size_t)(c + 2) * 64 + lane];
    int v3 = adj[(size_t)(c + 3) * 64 + lane];
    unsigned long long m0 = __ballot(v0 != 0);
    unsigned long long m1 = __ballot(v1 != 0);
    unsigned long long m2 = __ballot(v2 != 0);
    unsigned long long m3 = __ballot(v3 != 0);
    if (lane == 0) {
      bits[c + 0] = m0;
      bits[c + 1] = m1;
      bits[c + 2] = m2;
      bits[c + 3] = m3;
    }
  }
}

// ---------------- k1: projection -> fp16 transposed + s ----------------
__global__ __launch_bounds__(256) void proj_kernel(
    const float* __restrict__ x, const float* __restrict__ W,
    const float* __restrict__ bias, const float* __restrict__ a_w,
    const float* __restrict__ a_b, unsigned short* __restrict__ pT,
    float* __restrict__ s) {
  const int bid = blockIdx.x;
  const int nt = bid & 31;
  const int b = (bid >> 5) & 3;
  const int h = bid >> 7;
  const int n0 = nt * 64;

  __shared__ __align__(16) char smem[71168];
  float (*Wl)[Udim] = (float(*)[Udim])(smem);                  // 32768 B
  float (*xl)[Fdim + 4] = (float(*)[Fdim + 4])(smem + 32768);  // 33792 B
  float (*pt)[68] = (float(*)[68])(smem + 32768);              // alias xl
  float* bl = (float*)(smem + 66560);
  float* awl = (float*)(smem + 66816);
  float (*sred)[16] = (float(*)[16])(smem + 67072);            // 4096 B

  const int t = threadIdx.x;

  const float* Wg = W + (size_t)h * Fdim * Udim;
  for (int k = t; k < Fdim * Udim / 4; k += 256) {
    ((float4*)&Wl[0][0])[k] = ((const float4*)Wg)[k];
  }
  if (t < Udim) {
    bl[t] = bias[h * Udim + t];
    awl[t] = a_w[h * Udim + t];
  }
  const float* xg = x + ((size_t)b * Ndim + n0) * Fdim;
  for (int k = t; k < 64 * Fdim / 4; k += 256) {
    int row = k >> 5;
    int c4 = k & 31;
    float4 v = ((const float4*)xg)[(size_t)row * (Fdim / 4) + c4];
    *(float4*)&xl[row][c4 * 4] = v;
  }
  __syncthreads();

  const int ug = t & 15, rg = t >> 4;
  const int u0 = ug * 4, r0 = rg * 4;
  float acc[4][4] = {};

#pragma unroll 4
  for (int f = 0; f < Fdim; ++f) {
    const float4 wv = *(const float4*)&Wl[f][u0];
    const float xv[4] = {xl[r0][f], xl[r0 + 1][f], xl[r0 + 2][f], xl[r0 + 3][f]};
#pragma unroll
    for (int c = 0; c < 4; ++c) {
      acc[c][0] = fmaf(xv[c], wv.x, acc[c][0]);
      acc[c][1] = fmaf(xv[c], wv.y, acc[c][1]);
      acc[c][2] = fmaf(xv[c], wv.z, acc[c][2]);
      acc[c][3] = fmaf(xv[c], wv.w, acc[c][3]);
    }
  }

  float po[4][4];  // [c = n-offset][k = u-offset]
#pragma unroll
  for (int c = 0; c < 4; ++c)
#pragma unroll
    for (int k = 0; k < 4; ++k)
      po[c][k] = fmaxf(acc[c][k] + bl[u0 + k], 0.f);

#pragma unroll
  for (int c = 0; c < 4; ++c) {
    float sp = po[c][0] * awl[u0 + 0] + po[c][1] * awl[u0 + 1] +
               po[c][2] * awl[u0 + 2] + po[c][3] * awl[u0 + 3];
    sred[r0 + c][ug] = sp;
  }
  __syncthreads();  // all xl reads done; safe to overwrite via pt alias

#pragma unroll
  for (int k = 0; k < 4; ++k) {
    float4 v = {po[0][k], po[1][k], po[2][k], po[3][k]};
    *(float4*)&pt[u0 + k][r0] = v;
  }
  __syncthreads();

  const size_t hb = (size_t)h * Bdim + b;
  const int su = t >> 2;
  const int snl = (t & 3) * 16;
  float v[16];
#pragma unroll
  for (int j = 0; j < 4; ++j)
    *(float4*)&v[4 * j] = *(const float4*)&pt[su][snl + 4 * j];
  unsigned ow[8];
#pragma unroll
  for (int p2 = 0; p2 < 8; ++p2) {
    float2 fp;
    fp.x = v[2 * p2];
    fp.y = v[2 * p2 + 1];
    union { __half2 h; unsigned u; } cc;
    cc.h = __float22half2_rn(fp);
    ow[p2] = cc.u;
  }
  unsigned short* ph =
      pT + hb * (size_t)(Udim * Ndim) + (size_t)su * Ndim + n0 + snl;
  uint4 w0v; w0v.x = ow[0]; w0v.y = ow[1]; w0v.z = ow[2]; w0v.w = ow[3];
  uint4 w1v; w1v.x = ow[4]; w1v.y = ow[5]; w1v.z = ow[6]; w1v.w = ow[7];
  *(uint4*)(ph) = w0v;
  *(uint4*)(ph + 8) = w1v;

  if (t < 64) {
    float sum = a_b[h];
#pragma unroll
    for (int k = 0; k < 16; ++k) sum += sred[t][k];
    s[hb * Ndim + n0 + t] = sum;
  }
}

// ---------------- k2: MFMA masked-softmax aggregation, fp16 ----------------
// grid: 1024 blocks = XCD-swizzled (h:4, b:4, itile:32, jc:2), 256 threads.
// Per 32-j step/wave: 1 stage16 (k+2), vmcnt(1)+barrier (k+1 stays in
// flight), 8 exp2 (rescaled, fp16-safe), 4 cvt_pk, 4 ds_read_b128, 5 MFMA.
#define ASTEP(BPTR, JS)                                                        \
  do {                                                                         \
    const unsigned int mb = (ab[irow][(JS) >> 5] >> (q * 8)) & 0xffu;          \
    const f32x4 s0v = *(const f32x4*)&sj[(JS) + q * 8];                        \
    const f32x4 s1v = *(const f32x4*)&sj[(JS) + q * 8 + 4];                    \
    const float sv[8] = {s0v.x, s0v.y, s0v.z, s0v.w,                           \
                         s1v.x, s1v.y, s1v.z, s1v.w};                          \
    float w[8];                                                                \
    _Pragma("unroll") for (int e = 0; e < 8; ++e) {                            \
      float we = __builtin_amdgcn_exp2f(fmaf(si2, sv[e], nc));                 \
      w[e] = ((mb >> e) & 1u) ? we : 0.f;                                      \
    }                                                                          \
    union { half8 h; unsigned u[4]; } af;                                      \
    _Pragma("unroll") for (int p2 = 0; p2 < 4; ++p2) {                         \
      float2 fp;                                                               \
      fp.x = w[2 * p2];                                                        \
      fp.y = w[2 * p2 + 1];                                                    \
      union { __half2 h; unsigned u; } cc;                                     \
      cc.h = __float22half2_rn(fp);                                            \
      af.u[p2] = cc.u;                                                         \
    }                                                                          \
    const short* bp = (const short*)(BPTR);                                    \
    union { short8 s; half8 h; } b0, b1, b2, b3;                               \
    b0.s = *(const short8*)(bp + 0 * 512 + lane * 8);                          \
    b1.s = *(const short8*)(bp + 1 * 512 + lane * 8);                          \
    b2.s = *(const short8*)(bp + 2 * 512 + lane * 8);                          \
    b3.s = *(const short8*)(bp + 3 * 512 + lane * 8);                          \
    __builtin_amdgcn_s_setprio(1);                                             \
    acc[0] = __builtin_amdgcn_mfma_f32_16x16x32_f16(af.h, b0.h, acc[0],0,0,0); \
    acc[1] = __builtin_amdgcn_mfma_f32_16x16x32_f16(af.h, b1.h, acc[1],0,0,0); \
    acc[2] = __builtin_amdgcn_mfma_f32_16x16x32_f16(af.h, b2.h, acc[2],0,0,0); \
    acc[3] = __builtin_amdgcn_mfma_f32_16x16x32_f16(af.h, b3.h, acc[3],0,0,0); \
    accZ = __builtin_amdgcn_mfma_f32_16x16x32_f16(af.h, ones.h, accZ,0,0,0);   \
    __builtin_amdgcn_s_setprio(0);                                             \
  } while (0)

__global__ __launch_bounds__(256, 4) void attn_mfma_kernel(
    const unsigned short* __restrict__ pT, const float* __restrict__ s,
    const unsigned int* __restrict__ abits, float* __restrict__ out_part,
    float* __restrict__ Z_part) {
  // XCD swizzle: consecutive bids round-robin XCDs; give XCD x the groups
  // g with g%8==x so all 32 i-tile blocks of one (h,b,jc) share one L2.
  const int bid = blockIdx.x;
  const int xcd = bid & 7, slot = bid >> 3;
  const int g = xcd + ((slot >> 5) << 3);  // 0..31, bijective
  const int it = slot & 31;
  const int jc = g & 1;
  const int b = (g >> 1) & 3;
  const int h = g >> 3;
  const int i0g = it * 64;
  const int j0g = jc * JCHUNK;

  __shared__ float sj[JCHUNK];                    // 4 KB
  __shared__ unsigned int ab[64][33];             // 8.45 KB padded
  __shared__ __align__(16) short Bst[3][4][512];  // 12 KB triple buffer
  __shared__ float mred[4];

  const int t = threadIdx.x;
  const int wv = t >> 6;
  const int lane = t & 63;
  const int q = lane >> 4;
  const int li = lane & 15;
  const size_t hb = (size_t)h * Bdim + b;
  const float* sg = s + hb * Ndim;

  // full-row max|s| — computed identically by both jc blocks of this row
  float4 a0 = ((const float4*)sg)[t];
  float4 a1 = ((const float4*)sg)[t + 256];
  float mloc = fmaxf(
      fmaxf(fmaxf(fabsf(a0.x), fabsf(a0.y)), fmaxf(fabsf(a0.z), fabsf(a0.w))),
      fmaxf(fmaxf(fabsf(a1.x), fabsf(a1.y)), fmaxf(fabsf(a1.z), fabsf(a1.w))));
#pragma unroll
  for (int off = 1; off < 64; off <<= 1)
    mloc = fmaxf(mloc, __shfl_xor(mloc, off, 64));
  if (lane == 0) mred[wv] = mloc;

  ((float4*)sj)[t] = ((const float4*)(sg + j0g))[t];  // 1024 floats
  for (int k = t; k < 64 * 32; k += 256) {
    int row = k >> 5, w = k & 31;
    ab[row][w] =
        abits[((size_t)b * Ndim + i0g + row) * (Ndim / 32) + (j0g >> 5) + w];
  }
  const int irow = wv * 16 + li;
  const float si2 = sg[i0g + irow] * 1.4426950408889634f;  // si * log2(e)
  __syncthreads();
  const float M = fmaxf(fmaxf(mred[0], mred[1]), fmaxf(mred[2], mred[3]));
  const float nc = -fabsf(si2) * M;  // arg = si2*sj + nc <= 0 -> w' in (0,1]

  const unsigned short* bsrc =
      pT + hb * (size_t)(Udim * Ndim) + (size_t)(wv * 16 + li) * Ndim + j0g +
      q * 8;

  // stage steps 0,1 (1 KB per wave each: u-tile wv)
  stage16(bsrc + 0, &Bst[0][wv][0]);
  stage16(bsrc + 32, &Bst[1][wv][0]);

  f32x4 acc[4] = {};
  f32x4 accZ = {};
  union { half8 h; short8 s8; } ones;
#pragma unroll
  for (int e = 0; e < 8; ++e) ones.h[e] = (_Float16)1.0f;

  short* bS0 = &Bst[0][0][0];
  short* bS1 = &Bst[1][0][0];
  short* bS2 = &Bst[2][0][0];

  for (int js = 0; js < JCHUNK; js += 32) {
    // wait my stage(k); stage(k+1) stays in flight (counted vmcnt)
    asm volatile("s_waitcnt vmcnt(1)" ::: "memory");
    __builtin_amdgcn_s_barrier();
    __builtin_amdgcn_sched_barrier(0);
    const int jsn = (js + 64) & (JCHUNK - 1);  // tail wrap = dummy, never read
    stage16(bsrc + jsn, bS2 + wv * 512);
    ASTEP(bS0, js);
    short* tmp = bS0; bS0 = bS1; bS1 = bS2; bS2 = tmp;
  }

  const size_t pslab = ((size_t)h * JC + jc) * Bdim + b;
  // Z from ones-MFMA: all 16 cols identical; row = q*4+r (m89)
  if (li == 0) {
#pragma unroll
    for (int r = 0; r < 4; ++r)
      Z_part[pslab * Ndim + i0g + wv * 16 + q * 4 + r] = accZ[r];
  }

  // direct C-stores (D layout m89: col=li, row=q*4+r)
  float* op = out_part + (pslab * Ndim + i0g + wv * 16) * Udim;
#pragma unroll
  for (int r = 0; r < 4; ++r) {
    const int ir = q * 4 + r;
#pragma unroll
    for (int m = 0; m < 4; ++m) {
      op[(size_t)ir * Udim + m * 16 + li] = acc[m][r];
    }
  }
}

// ---------------- k3: combine partials, normalize, head-mean ----------------
__global__ __launch_bounds__(256) void combine_kernel(
    const float* __restrict__ out_part, const float* __restrict__ Z_part,
    float* __restrict__ out) {
  const int idx = blockIdx.x * 256 + threadIdx.x;
  const int u4 = idx & 15;
  const size_t bn = (size_t)(idx >> 4);
  float4 r = {0.f, 0.f, 0.f, 0.f};
#pragma unroll
  for (int h = 0; h < Hdim; ++h) {
    float4 p = {0.f, 0.f, 0.f, 0.f};
    float z = 0.f;
#pragma unroll
    for (int j = 0; j < JC; ++j) {
      const size_t sl = ((size_t)h * JC + j) * (Bdim * Ndim) + bn;
      float4 pj = ((const float4*)out_part)[sl * (Udim / 4) + u4];
      p.x += pj.x; p.y += pj.y; p.z += pj.z; p.w += pj.w;
      z += Z_part[sl];
    }
    z = (z != 0.f) ? z : 1.f;
    const float inv = 1.f / z;
    r.x += p.x * inv;
    r.y += p.y * inv;
    r.z += p.z * inv;
    r.w += p.w * inv;
  }
  r.x *= 0.25f; r.y *= 0.25f; r.z *= 0.25f; r.w *= 0.25f;
  ((float4*)out)[idx] = r;
}

extern "C" void kernel_launch(void* const* d_in, const int* in_sizes, int n_in,
                              void* d_out, int out_size, void* d_ws,
                              size_t ws_size, hipStream_t stream) {
  const float* x = (const float*)d_in[0];
  const int* adj = (const int*)d_in[1];
  const float* W = (const float*)d_in[2];
  const float* bias = (const float*)d_in[3];
  const float* a_w = (const float*)d_in[4];
  const float* a_b = (const float*)d_in[5];
  float* out = (float*)d_out;

  char* ws = (char*)d_ws;
  unsigned short* pT = (unsigned short*)(ws + 0);
  float* s = (float*)(ws + 4194304);
  unsigned int* adjbits = (unsigned int*)(ws + 4325376);
  float* out_part = (float*)(ws + 6422528);
  float* Z_part = (float*)(ws + 23199744);

  const int nchunks = Bdim * Ndim * Ndim / 64;  // 262144
  pack_adj_kernel<<<2048, 256, 0, stream>>>(adj, (unsigned long long*)adjbits,
                                            nchunks);
  proj_kernel<<<Hdim * Bdim * 32, 256, 0, stream>>>(x, W, bias, a_w, a_b, pT,
                                                    s);
  attn_mfma_kernel<<<Hdim * Bdim * 32 * JC, 256, 0, stream>>>(
      pT, s, adjbits, out_part, Z_part);
  combine_kernel<<<(Bdim * Ndim * Udim / 4) / 256, 256, 0, stream>>>(
      out_part, Z_part, out);
}